// Round 13
// baseline (294.439 us; speedup 1.0000x reference)
//
#include <hip/hip_runtime.h>
#include <hip/hip_bf16.h>
#include <stdint.h>

// SparseMoE: B=8,S=2048 -> 16384 tokens, D=512, E=10, H=2048, top-2.
// Sparse expert-grouped two-pass bf16 MFMA GEMM. Router in fp32.
// R7: m97 single-buffer 128x128/BK64 core. 4 blocks/CU TLP beats every
//     LDS-costing pipeline tried (R4/R5/R6/R9 all regressed).
// R10: LDS-histogram router/scatter + gemm1 LDS-restage epilogue -> 333us.
// R11: gemm2 -> bf16 ybuf + k_combine (atomics gone) -> 269us.
// R12: aux consolidation (6 launches) -> 268us (flat; aux at BW floor).
// R13: nontemporal hints (zero structural risk): nt-store hbuf/out
//      (read-once-later/never -> no L2 write-allocate pollution), nt-load
//      W f32 + x f32 (read-once), float4 prep loads. GEMM K-loops untouched.

#define N_TOK 16384
#define DIM 512
#define NEXP 10
#define HID 2048
#define BM 128
#define BN 128
#define BK 64
#define MAXSLOT (2*N_TOK + NEXP*BM)   // 34048 (each expert padded to 128)
#define NMB (MAXSLOT/BM)              // 266
#define RT_TOK 32                     // router tokens per block
#define NBN1 (HID/BN)                 // 16
#define NBN2 (DIM/BN)                 // 4

typedef __attribute__((ext_vector_type(8))) short bf16x8;   // 8 bf16 = 4 VGPR
typedef __attribute__((ext_vector_type(4))) float f32x4;

__device__ __forceinline__ unsigned short f2bf(float v) {
  __hip_bfloat16 h = __float2bfloat16(v);
  return *reinterpret_cast<unsigned short*>(&h);
}

__device__ __forceinline__ float bf2f(unsigned short u) {
  union { unsigned int i; float f; } c;
  c.i = ((unsigned int)u) << 16;
  return c.f;
}

__device__ __forceinline__ void gload_lds16(const void* g, void* l) {
  __builtin_amdgcn_global_load_lds(
      (__attribute__((address_space(1))) void*)g,
      (__attribute__((address_space(3))) void*)l, 16, 0, 0);
}

// bijective chunked XCD remap (m204)
__device__ __forceinline__ int xcd_chunk(int b, int nwg) {
  int q = nwg >> 3, r = nwg & 7;
  int xcd = b & 7, slot = b >> 3;
  return (xcd < r) ? (xcd*(q+1) + slot) : (r*(q+1) + (xcd-r)*q + slot);
}

// ---------------- prep: W1^T, W2^T (LDS 64x64 tiles), router-W cvt ----------------
__device__ __forceinline__ void transpose_tile(
    const float* __restrict__ in, unsigned short* __restrict__ outp,
    int R, int C, int b) {
  __shared__ float tile[64][65];
  int nTC = C >> 6;
  int tilesPerE = (R >> 6) * nTC;
  int e = b / tilesPerE;
  int t = b % tilesPerE;
  int rb = t / nTC, cb = t % nTC;
  const float* ip = in + ((size_t)e*R + (size_t)rb*64) * C + cb*64;
  // float4 nt loads: W is read exactly once (R13)
  int r4 = threadIdx.x >> 4;            // 0..15
  int c4 = (threadIdx.x & 15) * 4;      // 0..60
  #pragma unroll
  for (int p = 0; p < 4; ++p) {
    f32x4 v = __builtin_nontemporal_load((const f32x4*)&ip[(size_t)(r4 + p*16)*C + c4]);
    tile[r4 + p*16][c4+0] = v[0];
    tile[r4 + p*16][c4+1] = v[1];
    tile[r4 + p*16][c4+2] = v[2];
    tile[r4 + p*16][c4+3] = v[3];
  }
  __syncthreads();
  unsigned short* op = outp + ((size_t)e*C + (size_t)cb*64) * R + rb*64;
  int ro = threadIdx.x >> 2;            // out row 0..63
  int cc = (threadIdx.x & 3) * 16;      // out col chunk
  union { unsigned short us[8]; bf16x8 v; } pk;
  #pragma unroll
  for (int half = 0; half < 2; ++half) {
    #pragma unroll
    for (int j = 0; j < 8; ++j) pk.us[j] = f2bf(tile[cc + half*8 + j][ro]);
    *(bf16x8*)&op[(size_t)ro*R + cc + half*8] = pk.v;
  }
}

#define NT_W1 (NEXP*(DIM/64)*(HID/64))   // 2560
#define NT_W2 (NEXP*(HID/64)*(DIM/64))   // 2560

__global__ void k_prep(const float* __restrict__ W1, unsigned short* __restrict__ w1t,
                       const float* __restrict__ W2, unsigned short* __restrict__ w2t,
                       const float* __restrict__ Wr, const float* __restrict__ Wn,
                       float* __restrict__ wrt, float* __restrict__ wnt) {
  int b = blockIdx.x;
  if (b < NT_W1) {
    transpose_tile(W1, w1t, DIM, HID, b);
  } else if (b < NT_W1 + NT_W2) {
    transpose_tile(W2, w2t, HID, DIM, b - NT_W1);
  } else {
    for (int i = threadIdx.x; i < NEXP*DIM; i += 256) {
      int e = i / DIM, d = i % DIM;
      wrt[i] = Wr[d*NEXP + e];
      wnt[i] = Wn[d*NEXP + e];
    }
  }
}

// ---------------- router (fp32) + xb emission ----------------
__global__ __launch_bounds__(256) void k_router2x(
    const float* __restrict__ x, const float* __restrict__ noise,
    const float* __restrict__ wrt, const float* __restrict__ wnt,
    const float* __restrict__ br, const float* __restrict__ bnb,
    int* __restrict__ top_idx, float* __restrict__ top_gate, int* __restrict__ counts,
    unsigned short* __restrict__ xb) {
  __shared__ float part[8][RT_TOK][21];
  __shared__ float red[RT_TOK][21];
  __shared__ float vsh[RT_TOK][10];
  __shared__ int lcnt[16];
  int tid = threadIdx.x;
  int tl = tid & 31;          // token-local
  int g  = tid >> 5;          // d-group 0..7
  int tok = blockIdx.x * RT_TOK + tl;

  const f32x4* xr = (const f32x4*)(x + (size_t)tok*DIM + g*64);
  float acc[20];
  #pragma unroll
  for (int j = 0; j < 20; ++j) acc[j] = 0.f;

  f32x4 xprev;
  #pragma unroll 4
  for (int c = 0; c < 16; ++c) {
    f32x4 xv = __builtin_nontemporal_load(&xr[c]);   // x read exactly once (R13)
    int d = g*64 + c*4;
    #pragma unroll
    for (int e = 0; e < NEXP; ++e) {
      f32x4 a = *(const f32x4*)(wrt + e*DIM + d);
      f32x4 b = *(const f32x4*)(wnt + e*DIM + d);
      acc[e]    += xv[0]*a[0] + xv[1]*a[1] + xv[2]*a[2] + xv[3]*a[3];
      acc[10+e] += xv[0]*b[0] + xv[1]*b[1] + xv[2]*b[2] + xv[3]*b[3];
    }
    // pack 2 f32x4 -> 8 bf16 -> one 16B store (fuses the old k_cvt_x)
    if (c & 1) {
      union { unsigned short us[8]; uint4 u4; } p;
      p.us[0]=f2bf(xprev[0]); p.us[1]=f2bf(xprev[1]); p.us[2]=f2bf(xprev[2]); p.us[3]=f2bf(xprev[3]);
      p.us[4]=f2bf(xv[0]);    p.us[5]=f2bf(xv[1]);    p.us[6]=f2bf(xv[2]);    p.us[7]=f2bf(xv[3]);
      *(uint4*)&xb[(size_t)tok*DIM + g*64 + (c-1)*4] = p.u4;
    } else {
      xprev = xv;
    }
  }
  #pragma unroll
  for (int j = 0; j < 20; ++j) part[g][tl][j] = acc[j];
  __syncthreads();

  for (int o = tid; o < RT_TOK*20; o += 256) {
    int t2 = o / 20, j = o % 20;
    float s = 0.f;
    #pragma unroll
    for (int gg = 0; gg < 8; ++gg) s += part[gg][t2][j];
    red[t2][j] = s;
  }
  __syncthreads();

  for (int o = tid; o < RT_TOK*NEXP; o += 256) {
    int t2 = o / NEXP, e = o % NEXP;
    float nl = red[t2][10+e] + bnb[e];
    float sp = (nl > 20.f) ? nl : log1pf(expf(nl));
    vsh[t2][e] = red[t2][e] + br[e]
               + noise[(size_t)(blockIdx.x*RT_TOK + t2)*NEXP + e] * sp;
  }
  if (tid < 16) lcnt[tid] = 0;
  __syncthreads();

  if (tid < RT_TOK) {
    int t2 = tid;
    float v0 = -1e30f, v1 = -1e30f; int i0 = 0, i1 = 0;
    #pragma unroll
    for (int e = 0; e < NEXP; ++e) {
      float v = vsh[t2][e];
      if (v > v0) { v1 = v0; i1 = i0; v0 = v; i0 = e; }
      else if (v > v1) { v1 = v; i1 = e; }
    }
    float ev = expf(v1 - v0);
    float g0 = 1.f / (1.f + ev);
    float g1 = ev / (1.f + ev);
    int tk = blockIdx.x * RT_TOK + t2;
    top_idx[tk*2] = i0; top_idx[tk*2+1] = i1;
    top_gate[tk*2] = g0; top_gate[tk*2+1] = g1;
    atomicAdd(&lcnt[i0], 1);
    atomicAdd(&lcnt[i1], 1);
  }
  __syncthreads();
  if (tid < NEXP && lcnt[tid] > 0) atomicAdd(&counts[tid], lcnt[tid]);
}

// ---------------- scatter (offs computed in-block) ----------------
__global__ __launch_bounds__(256) void k_scatter2(
    const int* __restrict__ top_idx, const int* __restrict__ counts,
    int* __restrict__ cursors, int* __restrict__ offs_g,
    int* __restrict__ slot_token, int* __restrict__ tok_slot) {
  __shared__ int lcnt[16];
  __shared__ int lbase[16];
  __shared__ int loffs[12];
  int tid = threadIdx.x;
  int t = blockIdx.x * 256 + tid;
  if (tid < 16) lcnt[tid] = 0;
  if (tid == 0) {
    int acc = 0;
    #pragma unroll
    for (int e = 0; e < NEXP; ++e) {
      loffs[e] = acc;
      acc += ((counts[e] + BM - 1) / BM) * BM;
    }
    loffs[NEXP] = acc;
  }
  __syncthreads();
  int e0 = top_idx[t*2], e1 = top_idx[t*2+1];
  int r0 = atomicAdd(&lcnt[e0], 1);
  int r1 = atomicAdd(&lcnt[e1], 1);
  __syncthreads();
  if (tid < NEXP && lcnt[tid] > 0) lbase[tid] = atomicAdd(&cursors[tid], lcnt[tid]);
  __syncthreads();
  int p0 = loffs[e0] + lbase[e0] + r0;
  int p1 = loffs[e1] + lbase[e1] + r1;
  slot_token[p0] = t;
  slot_token[p1] = t;
  tok_slot[t*2]   = p0;
  tok_slot[t*2+1] = p1;
  if (blockIdx.x == 0 && tid <= NEXP) offs_g[tid] = loffs[tid];
}

// ---------------- GEMM1: h = relu(gather(x) @ W1[e] + b1[e]) ---- (R11-verified core)
__global__ __launch_bounds__(256, 4) void k_gemm1(
    const unsigned short* __restrict__ xb, const unsigned short* __restrict__ w1t,
    const float* __restrict__ b1, const int* __restrict__ slot_token,
    const int* __restrict__ offs, unsigned short* __restrict__ h) {
  __shared__ unsigned short smem[2*BM*BK];   // As | Bs ; reused as C tile
  unsigned short* As = smem;
  unsigned short* Bs = smem + BM*BK;
  int w = xcd_chunk(blockIdx.x, NMB*NBN1);
  int bm = w / NBN1, bn = w % NBN1;
  int tid = threadIdx.x, wid = tid >> 6, lane = tid & 63;
  int s0 = bm * BM;
  int e = 0;
  #pragma unroll
  for (int i = 1; i < NEXP; ++i) if (s0 >= offs[i]) e = i;

  int tokA[4];
  #pragma unroll
  for (int i = 0; i < 4; ++i) {
    int r = (i*4 + wid)*8 + (lane >> 3);
    int t = slot_token[s0 + r];
    tokA[i] = t < 0 ? 0 : t;
  }
  int kcs = ((lane & 7) ^ (lane >> 3)) * 8;     // swizzled global col (elements)
  int ldst = (lane & 7) * 8;                    // linear LDS col (elements)
  const unsigned short* w1te = w1t + ((size_t)e*HID + (size_t)bn*BN) * DIM;

  f32x4 acc[4][4];
  #pragma unroll
  for (int m=0;m<4;m++)
    #pragma unroll
    for (int n=0;n<4;n++) acc[m][n] = (f32x4){0.f,0.f,0.f,0.f};

  int wr = wid >> 1, wc = wid & 1;
  int xr = (lane & 7) * 8;                      // read-side XOR term

  for (int kt = 0; kt < DIM/BK; ++kt) {
    int k0 = kt * BK;
    #pragma unroll
    for (int i = 0; i < 4; ++i) {
      int r = (i*4 + wid)*8 + (lane >> 3);
      gload_lds16(xb + (size_t)tokA[i]*DIM + k0 + kcs, &As[r*BK + ldst]);
      gload_lds16(w1te + (size_t)r*DIM + k0 + kcs, &Bs[r*BK + ldst]);
    }
    __syncthreads();
    #pragma unroll
    for (int ks = 0; ks < 2; ++ks) {
      int kk = (ks*32 + (lane >> 4)*8) ^ xr;
      bf16x8 a[4], b[4];
      #pragma unroll
      for (int m=0;m<4;m++) a[m] = *(const bf16x8*)&As[(wr*64 + m*16 + (lane&15))*BK + kk];
      #pragma unroll
      for (int n=0;n<4;n++) b[n] = *(const bf16x8*)&Bs[(wc*64 + n*16 + (lane&15))*BK + kk];
      #pragma unroll
      for (int m=0;m<4;m++)
        #pragma unroll
        for (int n=0;n<4;n++)
          acc[m][n] = __builtin_amdgcn_mfma_f32_16x16x32_bf16(a[m], b[n], acc[m][n], 0,0,0);
    }
    __syncthreads();
  }

  // epilogue: bias+relu -> LDS C tile (chunk-XOR swizzled) -> coalesced NT store
  unsigned short* ct = smem;
  #pragma unroll
  for (int m=0;m<4;m++){
    int row0 = wr*64 + m*16 + (lane>>4)*4;
    #pragma unroll
    for (int n=0;n<4;n++){
      int lcol = wc*64 + n*16 + (lane&15);
      float bias = b1[e*HID + bn*BN + lcol];
      #pragma unroll
      for (int r=0;r<4;r++){
        int row = row0 + r;
        float v = acc[m][n][r] + bias;
        v = v > 0.f ? v : 0.f;
        int pc = (lcol >> 3) ^ (row & 7);
        ct[row*BN + (pc<<3) + (lcol&7)] = f2bf(v);
      }
    }
  }
  __syncthreads();
  int cchunk = tid & 15, rbase = tid >> 4;
  unsigned short* hb = h + (size_t)s0*HID + bn*BN;
  #pragma unroll
  for (int j=0;j<8;j++){
    int row = rbase + j*16;
    int pc = cchunk ^ (row & 7);
    bf16x8 v = *(const bf16x8*)&ct[row*BN + (pc<<3)];
    // hbuf (139.5MB) is read only by gemm2, much later -> nt (R13)
    __builtin_nontemporal_store(v, (bf16x8*)&hb[(size_t)row*HID + cchunk*8]);
  }
}

// ---------------- GEMM2: ybuf[slot] = bf16(h @ W2[e] + b2[e]) ---- (R11-verified)
__global__ __launch_bounds__(256, 4) void k_gemm2(
    const unsigned short* __restrict__ h, const unsigned short* __restrict__ w2t,
    const float* __restrict__ b2, const int* __restrict__ offs,
    unsigned short* __restrict__ ybuf) {
  __shared__ unsigned short smem[2*BM*BK];
  unsigned short* As = smem;
  unsigned short* Bs = smem + BM*BK;
  int w = xcd_chunk(blockIdx.x, NMB*NBN2);
  int bm = w / NBN2, bn = w % NBN2;
  int tid = threadIdx.x, wid = tid >> 6, lane = tid & 63;
  int s0 = bm * BM;
  int e = 0;
  #pragma unroll
  for (int i = 1; i < NEXP; ++i) if (s0 >= offs[i]) e = i;
  int kcs = ((lane & 7) ^ (lane >> 3)) * 8;
  int ldst = (lane & 7) * 8;
  const unsigned short* w2te = w2t + ((size_t)e*DIM + (size_t)bn*BN) * HID;

  f32x4 acc[4][4];
  #pragma unroll
  for (int m=0;m<4;m++)
    #pragma unroll
    for (int n=0;n<4;n++) acc[m][n] = (f32x4){0.f,0.f,0.f,0.f};

  int wr = wid >> 1, wc = wid & 1;
  int xr = (lane & 7) * 8;

  for (int kt = 0; kt < HID/BK; ++kt) {
    int k0 = kt * BK;
    #pragma unroll
    for (int i = 0; i < 4; ++i) {
      int r = (i*4 + wid)*8 + (lane >> 3);
      gload_lds16(h + (size_t)(s0 + r)*HID + k0 + kcs, &As[r*BK + ldst]);
      gload_lds16(w2te + (size_t)r*HID + k0 + kcs, &Bs[r*BK + ldst]);
    }
    __syncthreads();
    #pragma unroll
    for (int ks = 0; ks < 2; ++ks) {
      int kk = (ks*32 + (lane >> 4)*8) ^ xr;
      bf16x8 a[4], b[4];
      #pragma unroll
      for (int m=0;m<4;m++) a[m] = *(const bf16x8*)&As[(wr*64 + m*16 + (lane&15))*BK + kk];
      #pragma unroll
      for (int n=0;n<4;n++) b[n] = *(const bf16x8*)&Bs[(wc*64 + n*16 + (lane&15))*BK + kk];
      #pragma unroll
      for (int m=0;m<4;m++)
        #pragma unroll
        for (int n=0;n<4;n++)
          acc[m][n] = __builtin_amdgcn_mfma_f32_16x16x32_bf16(a[m], b[n], acc[m][n], 0,0,0);
    }
    __syncthreads();
  }

  unsigned short* ct = smem;
  #pragma unroll
  for (int m=0;m<4;m++){
    int row0 = wr*64 + m*16 + (lane>>4)*4;
    #pragma unroll
    for (int n=0;n<4;n++){
      int lcol = wc*64 + n*16 + (lane&15);
      float bias = b2[e*DIM + bn*BN + lcol];
      #pragma unroll
      for (int r=0;r<4;r++){
        int row = row0 + r;
        int pc = (lcol >> 3) ^ (row & 7);
        ct[row*BN + (pc<<3) + (lcol&7)] = f2bf(acc[m][n][r] + bias);
      }
    }
  }
  __syncthreads();
  int cchunk = tid & 15, rbase = tid >> 4;
  unsigned short* yb = ybuf + (size_t)s0*DIM + bn*BN;
  #pragma unroll
  for (int j=0;j<8;j++){
    int row = rbase + j*16;
    int pc = cchunk ^ (row & 7);
    bf16x8 v = *(const bf16x8*)&ct[row*BN + (pc<<3)];
    *(bf16x8*)&yb[(size_t)row*DIM + cchunk*8] = v;   // re-read soon by combine: keep cached
  }
}

// ---------------- combine: out[t] = g0*y[s0] + g1*y[s1] ----------------
__global__ __launch_bounds__(256) void k_combine(
    const unsigned short* __restrict__ ybuf, const int* __restrict__ tok_slot,
    const float* __restrict__ top_gate, float* __restrict__ out) {
  int gid = blockIdx.x * 256 + threadIdx.x;
  int t = gid >> 6, j = (gid & 63) * 8;
  int s0 = tok_slot[t*2], s1 = tok_slot[t*2+1];
  float g0 = top_gate[t*2], g1 = top_gate[t*2+1];
  union { bf16x8 v; unsigned short us[8]; } y0, y1;
  y0.v = *(const bf16x8*)&ybuf[(size_t)s0*DIM + j];
  y1.v = *(const bf16x8*)&ybuf[(size_t)s1*DIM + j];
  f32x4 o0, o1;
  #pragma unroll
  for (int i = 0; i < 4; ++i) o0[i] = g0*bf2f(y0.us[i])   + g1*bf2f(y1.us[i]);
  #pragma unroll
  for (int i = 0; i < 4; ++i) o1[i] = g0*bf2f(y0.us[4+i]) + g1*bf2f(y1.us[4+i]);
  f32x4* dst = (f32x4*)&out[(size_t)t*DIM + j];
  __builtin_nontemporal_store(o0, dst);       // out never re-read on device (R13)
  __builtin_nontemporal_store(o1, dst + 1);
}

extern "C" void kernel_launch(void* const* d_in, const int* in_sizes, int n_in,
                              void* d_out, int out_size, void* d_ws, size_t ws_size,
                              hipStream_t stream) {
  const float* x   = (const float*)d_in[0];
  const float* noi = (const float*)d_in[1];
  const float* Wr  = (const float*)d_in[2];
  const float* br  = (const float*)d_in[3];
  const float* Wn  = (const float*)d_in[4];
  const float* bnb = (const float*)d_in[5];
  const float* W1  = (const float*)d_in[6];
  const float* b1  = (const float*)d_in[7];
  const float* W2  = (const float*)d_in[8];
  const float* b2  = (const float*)d_in[9];
  float* out = (float*)d_out;
  (void)in_sizes; (void)n_in; (void)ws_size; (void)out_size;

  char* ws = (char*)d_ws;
  size_t off = 0;
  auto alloc = [&](size_t bytes) -> void* {
    void* p = ws + off; off += (bytes + 255) & ~(size_t)255; return p;
  };
  // ORDER MATTERS: w1t then xb (both dead after gemm1) form a contiguous
  // 37,748,736 B region that ybuf (34,865,152 B) aliases. w2t comes AFTER.
  unsigned short* w1t  = (unsigned short*)alloc((size_t)NEXP*HID*DIM*2);  // 21.0 MB @0
  unsigned short* xb   = (unsigned short*)alloc((size_t)N_TOK*DIM*2);     // 16.8 MB
  unsigned short* w2t  = (unsigned short*)alloc((size_t)NEXP*DIM*HID*2);  // 21.0 MB (live in gemm2)
  unsigned short* hbuf = (unsigned short*)alloc((size_t)MAXSLOT*HID*2);   // 139.5 MB
  float* wrt = (float*)alloc(NEXP*DIM*4);
  float* wnt = (float*)alloc(NEXP*DIM*4);
  int*   top_idx  = (int*)alloc(N_TOK*2*4);
  float* top_gate = (float*)alloc(N_TOK*2*4);
  int*   slot_token = (int*)alloc((size_t)MAXSLOT*4);
  int*   tok_slot   = (int*)alloc((size_t)N_TOK*2*4);
  int*   ctrl = (int*)alloc(64*4);
  int* counts  = ctrl;        // [10]
  int* cursors = ctrl + 10;   // [10]
  int* offs    = ctrl + 20;   // [11]
  unsigned short* ybuf = w1t;   // alias checked numerically (R8 lesson)

  hipMemsetAsync(ctrl, 0, 64*4, stream);
  hipMemsetAsync(slot_token, 0xFF, (size_t)MAXSLOT*4, stream);  // -1 fill

  k_prep<<<NT_W1 + NT_W2 + 1, 256, 0, stream>>>(W1, w1t, W2, w2t, Wr, Wn, wrt, wnt);
  k_router2x<<<N_TOK/RT_TOK, 256, 0, stream>>>(x, noi, wrt, wnt, br, bnb,
                                               top_idx, top_gate, counts, xb);
  k_scatter2<<<N_TOK/256, 256, 0, stream>>>(top_idx, counts, cursors, offs,
                                            slot_token, tok_slot);
  k_gemm1<<<NMB*NBN1, 256, 0, stream>>>(xb, w1t, b1, slot_token, offs, hbuf);
  k_gemm2<<<NMB*NBN2, 256, 0, stream>>>(hbuf, w2t, b2, offs, ybuf);
  k_combine<<<(N_TOK*64)/256, 256, 0, stream>>>(ybuf, tok_slot, top_gate, out);
}

// Round 14
// 267.902 us; speedup vs baseline: 1.0991x; 1.0991x over previous
//
#include <hip/hip_runtime.h>
#include <hip/hip_bf16.h>
#include <stdint.h>

// SparseMoE: B=8,S=2048 -> 16384 tokens, D=512, E=10, H=2048, top-2.
// Sparse expert-grouped two-pass bf16 MFMA GEMM. Router in fp32.
// R7: m97 single-buffer 128x128/BK64 core. 4 blocks/CU TLP beats every
//     LDS-costing pipeline tried (R4/R5/R6/R9 all regressed).
// R10: LDS-histogram router/scatter + gemm1 LDS-restage epilogue -> 333us.
// R11: gemm2 -> bf16 ybuf + k_combine (atomics gone) -> 269us.
// R12: aux consolidation (6 launches) -> 268us. VERIFIED BEST.
// R13: nontemporal hints REGRESSED (294us): nt-store on hbuf killed the
//      gemm1->gemm2 producer->consumer L2/L3 reuse; nt-loads forfeited L3
//      residency. Lesson: never nt-hint a buffer the next dispatch reads.
// R14: exact revert to R12.

#define N_TOK 16384
#define DIM 512
#define NEXP 10
#define HID 2048
#define BM 128
#define BN 128
#define BK 64
#define MAXSLOT (2*N_TOK + NEXP*BM)   // 34048 (each expert padded to 128)
#define NMB (MAXSLOT/BM)              // 266
#define RT_TOK 32                     // router tokens per block
#define NBN1 (HID/BN)                 // 16
#define NBN2 (DIM/BN)                 // 4

typedef __attribute__((ext_vector_type(8))) short bf16x8;   // 8 bf16 = 4 VGPR
typedef __attribute__((ext_vector_type(4))) float f32x4;

__device__ __forceinline__ unsigned short f2bf(float v) {
  __hip_bfloat16 h = __float2bfloat16(v);
  return *reinterpret_cast<unsigned short*>(&h);
}

__device__ __forceinline__ float bf2f(unsigned short u) {
  union { unsigned int i; float f; } c;
  c.i = ((unsigned int)u) << 16;
  return c.f;
}

__device__ __forceinline__ void gload_lds16(const void* g, void* l) {
  __builtin_amdgcn_global_load_lds(
      (__attribute__((address_space(1))) void*)g,
      (__attribute__((address_space(3))) void*)l, 16, 0, 0);
}

// bijective chunked XCD remap (m204)
__device__ __forceinline__ int xcd_chunk(int b, int nwg) {
  int q = nwg >> 3, r = nwg & 7;
  int xcd = b & 7, slot = b >> 3;
  return (xcd < r) ? (xcd*(q+1) + slot) : (r*(q+1) + (xcd-r)*q + slot);
}

// ---------------- prep: W1^T, W2^T (LDS 64x64 tiles), router-W cvt ----------------
__device__ __forceinline__ void transpose_tile(
    const float* __restrict__ in, unsigned short* __restrict__ outp,
    int R, int C, int b) {
  __shared__ float tile[64][65];
  int nTC = C >> 6;
  int tilesPerE = (R >> 6) * nTC;
  int e = b / tilesPerE;
  int t = b % tilesPerE;
  int rb = t / nTC, cb = t % nTC;
  int tr = threadIdx.x >> 6, tc = threadIdx.x & 63;
  const float* ip = in + ((size_t)e*R + (size_t)rb*64) * C + cb*64;
  #pragma unroll
  for (int p = 0; p < 16; ++p)
    tile[p*4 + tr][tc] = ip[(size_t)(p*4 + tr)*C + tc];
  __syncthreads();
  unsigned short* op = outp + ((size_t)e*C + (size_t)cb*64) * R + rb*64;
  int ro = threadIdx.x >> 2;            // out row 0..63
  int cc = (threadIdx.x & 3) * 16;      // out col chunk
  union { unsigned short us[8]; bf16x8 v; } pk;
  #pragma unroll
  for (int half = 0; half < 2; ++half) {
    #pragma unroll
    for (int j = 0; j < 8; ++j) pk.us[j] = f2bf(tile[cc + half*8 + j][ro]);
    *(bf16x8*)&op[(size_t)ro*R + cc + half*8] = pk.v;
  }
}

#define NT_W1 (NEXP*(DIM/64)*(HID/64))   // 2560
#define NT_W2 (NEXP*(HID/64)*(DIM/64))   // 2560

__global__ void k_prep(const float* __restrict__ W1, unsigned short* __restrict__ w1t,
                       const float* __restrict__ W2, unsigned short* __restrict__ w2t,
                       const float* __restrict__ Wr, const float* __restrict__ Wn,
                       float* __restrict__ wrt, float* __restrict__ wnt) {
  int b = blockIdx.x;
  if (b < NT_W1) {
    transpose_tile(W1, w1t, DIM, HID, b);
  } else if (b < NT_W1 + NT_W2) {
    transpose_tile(W2, w2t, HID, DIM, b - NT_W1);
  } else {
    for (int i = threadIdx.x; i < NEXP*DIM; i += 256) {
      int e = i / DIM, d = i % DIM;
      wrt[i] = Wr[d*NEXP + e];
      wnt[i] = Wn[d*NEXP + e];
    }
  }
}

// ---------------- router (fp32) + xb emission ----------------
__global__ __launch_bounds__(256) void k_router2x(
    const float* __restrict__ x, const float* __restrict__ noise,
    const float* __restrict__ wrt, const float* __restrict__ wnt,
    const float* __restrict__ br, const float* __restrict__ bnb,
    int* __restrict__ top_idx, float* __restrict__ top_gate, int* __restrict__ counts,
    unsigned short* __restrict__ xb) {
  __shared__ float part[8][RT_TOK][21];
  __shared__ float red[RT_TOK][21];
  __shared__ float vsh[RT_TOK][10];
  __shared__ int lcnt[16];
  int tid = threadIdx.x;
  int tl = tid & 31;          // token-local
  int g  = tid >> 5;          // d-group 0..7
  int tok = blockIdx.x * RT_TOK + tl;

  const float4* xr = (const float4*)(x + (size_t)tok*DIM + g*64);
  float acc[20];
  #pragma unroll
  for (int j = 0; j < 20; ++j) acc[j] = 0.f;

  float4 xprev;
  #pragma unroll 4
  for (int c = 0; c < 16; ++c) {
    float4 xv = xr[c];
    int d = g*64 + c*4;
    #pragma unroll
    for (int e = 0; e < NEXP; ++e) {
      float4 a = *(const float4*)(wrt + e*DIM + d);
      float4 b = *(const float4*)(wnt + e*DIM + d);
      acc[e]      += xv.x*a.x + xv.y*a.y + xv.z*a.z + xv.w*a.w;
      acc[10+e]   += xv.x*b.x + xv.y*b.y + xv.z*b.z + xv.w*b.w;
    }
    // pack 2 float4s -> 8 bf16 -> one 16B store (fuses the old k_cvt_x)
    if (c & 1) {
      union { unsigned short us[8]; uint4 u4; } p;
      p.us[0]=f2bf(xprev.x); p.us[1]=f2bf(xprev.y); p.us[2]=f2bf(xprev.z); p.us[3]=f2bf(xprev.w);
      p.us[4]=f2bf(xv.x);    p.us[5]=f2bf(xv.y);    p.us[6]=f2bf(xv.z);    p.us[7]=f2bf(xv.w);
      *(uint4*)&xb[(size_t)tok*DIM + g*64 + (c-1)*4] = p.u4;
    } else {
      xprev = xv;
    }
  }
  #pragma unroll
  for (int j = 0; j < 20; ++j) part[g][tl][j] = acc[j];
  __syncthreads();

  for (int o = tid; o < RT_TOK*20; o += 256) {
    int t2 = o / 20, j = o % 20;
    float s = 0.f;
    #pragma unroll
    for (int gg = 0; gg < 8; ++gg) s += part[gg][t2][j];
    red[t2][j] = s;
  }
  __syncthreads();

  for (int o = tid; o < RT_TOK*NEXP; o += 256) {
    int t2 = o / NEXP, e = o % NEXP;
    float nl = red[t2][10+e] + bnb[e];
    float sp = (nl > 20.f) ? nl : log1pf(expf(nl));
    vsh[t2][e] = red[t2][e] + br[e]
               + noise[(size_t)(blockIdx.x*RT_TOK + t2)*NEXP + e] * sp;
  }
  if (tid < 16) lcnt[tid] = 0;
  __syncthreads();

  if (tid < RT_TOK) {
    int t2 = tid;
    float v0 = -1e30f, v1 = -1e30f; int i0 = 0, i1 = 0;
    #pragma unroll
    for (int e = 0; e < NEXP; ++e) {
      float v = vsh[t2][e];
      if (v > v0) { v1 = v0; i1 = i0; v0 = v; i0 = e; }
      else if (v > v1) { v1 = v; i1 = e; }
    }
    float ev = expf(v1 - v0);
    float g0 = 1.f / (1.f + ev);
    float g1 = ev / (1.f + ev);
    int tk = blockIdx.x * RT_TOK + t2;
    top_idx[tk*2] = i0; top_idx[tk*2+1] = i1;
    top_gate[tk*2] = g0; top_gate[tk*2+1] = g1;
    atomicAdd(&lcnt[i0], 1);
    atomicAdd(&lcnt[i1], 1);
  }
  __syncthreads();
  if (tid < NEXP && lcnt[tid] > 0) atomicAdd(&counts[tid], lcnt[tid]);
}

// ---------------- scatter (offs computed in-block; k_offsets folded in) ----------------
__global__ __launch_bounds__(256) void k_scatter2(
    const int* __restrict__ top_idx, const int* __restrict__ counts,
    int* __restrict__ cursors, int* __restrict__ offs_g,
    int* __restrict__ slot_token, int* __restrict__ tok_slot) {
  __shared__ int lcnt[16];
  __shared__ int lbase[16];
  __shared__ int loffs[12];
  int tid = threadIdx.x;
  int t = blockIdx.x * 256 + tid;
  if (tid < 16) lcnt[tid] = 0;
  if (tid == 0) {
    int acc = 0;
    #pragma unroll
    for (int e = 0; e < NEXP; ++e) {
      loffs[e] = acc;
      acc += ((counts[e] + BM - 1) / BM) * BM;
    }
    loffs[NEXP] = acc;
  }
  __syncthreads();
  int e0 = top_idx[t*2], e1 = top_idx[t*2+1];
  int r0 = atomicAdd(&lcnt[e0], 1);
  int r1 = atomicAdd(&lcnt[e1], 1);
  __syncthreads();
  if (tid < NEXP && lcnt[tid] > 0) lbase[tid] = atomicAdd(&cursors[tid], lcnt[tid]);
  __syncthreads();
  int p0 = loffs[e0] + lbase[e0] + r0;
  int p1 = loffs[e1] + lbase[e1] + r1;
  slot_token[p0] = t;
  slot_token[p1] = t;
  tok_slot[t*2]   = p0;
  tok_slot[t*2+1] = p1;
  if (blockIdx.x == 0 && tid <= NEXP) offs_g[tid] = loffs[tid];
}

// ---------------- GEMM1: h = relu(gather(x) @ W1[e] + b1[e]) ---- (R11-verified)
__global__ __launch_bounds__(256, 4) void k_gemm1(
    const unsigned short* __restrict__ xb, const unsigned short* __restrict__ w1t,
    const float* __restrict__ b1, const int* __restrict__ slot_token,
    const int* __restrict__ offs, unsigned short* __restrict__ h) {
  __shared__ unsigned short smem[2*BM*BK];   // As | Bs ; reused as C tile
  unsigned short* As = smem;
  unsigned short* Bs = smem + BM*BK;
  int w = xcd_chunk(blockIdx.x, NMB*NBN1);
  int bm = w / NBN1, bn = w % NBN1;
  int tid = threadIdx.x, wid = tid >> 6, lane = tid & 63;
  int s0 = bm * BM;
  int e = 0;
  #pragma unroll
  for (int i = 1; i < NEXP; ++i) if (s0 >= offs[i]) e = i;

  int tokA[4];
  #pragma unroll
  for (int i = 0; i < 4; ++i) {
    int r = (i*4 + wid)*8 + (lane >> 3);
    int t = slot_token[s0 + r];
    tokA[i] = t < 0 ? 0 : t;
  }
  int kcs = ((lane & 7) ^ (lane >> 3)) * 8;     // swizzled global col (elements)
  int ldst = (lane & 7) * 8;                    // linear LDS col (elements)
  const unsigned short* w1te = w1t + ((size_t)e*HID + (size_t)bn*BN) * DIM;

  f32x4 acc[4][4];
  #pragma unroll
  for (int m=0;m<4;m++)
    #pragma unroll
    for (int n=0;n<4;n++) acc[m][n] = (f32x4){0.f,0.f,0.f,0.f};

  int wr = wid >> 1, wc = wid & 1;
  int xr = (lane & 7) * 8;                      // read-side XOR term

  for (int kt = 0; kt < DIM/BK; ++kt) {
    int k0 = kt * BK;
    #pragma unroll
    for (int i = 0; i < 4; ++i) {
      int r = (i*4 + wid)*8 + (lane >> 3);
      gload_lds16(xb + (size_t)tokA[i]*DIM + k0 + kcs, &As[r*BK + ldst]);
      gload_lds16(w1te + (size_t)r*DIM + k0 + kcs, &Bs[r*BK + ldst]);
    }
    __syncthreads();
    #pragma unroll
    for (int ks = 0; ks < 2; ++ks) {
      int kk = (ks*32 + (lane >> 4)*8) ^ xr;
      bf16x8 a[4], b[4];
      #pragma unroll
      for (int m=0;m<4;m++) a[m] = *(const bf16x8*)&As[(wr*64 + m*16 + (lane&15))*BK + kk];
      #pragma unroll
      for (int n=0;n<4;n++) b[n] = *(const bf16x8*)&Bs[(wc*64 + n*16 + (lane&15))*BK + kk];
      #pragma unroll
      for (int m=0;m<4;m++)
        #pragma unroll
        for (int n=0;n<4;n++)
          acc[m][n] = __builtin_amdgcn_mfma_f32_16x16x32_bf16(a[m], b[n], acc[m][n], 0,0,0);
    }
    __syncthreads();
  }

  // epilogue: bias+relu -> LDS C tile (chunk-XOR swizzled) -> coalesced store
  unsigned short* ct = smem;
  #pragma unroll
  for (int m=0;m<4;m++){
    int row0 = wr*64 + m*16 + (lane>>4)*4;
    #pragma unroll
    for (int n=0;n<4;n++){
      int lcol = wc*64 + n*16 + (lane&15);
      float bias = b1[e*HID + bn*BN + lcol];
      #pragma unroll
      for (int r=0;r<4;r++){
        int row = row0 + r;
        float v = acc[m][n][r] + bias;
        v = v > 0.f ? v : 0.f;
        int pc = (lcol >> 3) ^ (row & 7);
        ct[row*BN + (pc<<3) + (lcol&7)] = f2bf(v);
      }
    }
  }
  __syncthreads();
  int cchunk = tid & 15, rbase = tid >> 4;
  unsigned short* hb = h + (size_t)s0*HID + bn*BN;
  #pragma unroll
  for (int j=0;j<8;j++){
    int row = rbase + j*16;
    int pc = cchunk ^ (row & 7);
    bf16x8 v = *(const bf16x8*)&ct[row*BN + (pc<<3)];
    *(bf16x8*)&hb[(size_t)row*HID + cchunk*8] = v;
  }
}

// ---------------- GEMM2: ybuf[slot] = bf16(h @ W2[e] + b2[e]) ---- (R11-verified)
__global__ __launch_bounds__(256, 4) void k_gemm2(
    const unsigned short* __restrict__ h, const unsigned short* __restrict__ w2t,
    const float* __restrict__ b2, const int* __restrict__ offs,
    unsigned short* __restrict__ ybuf) {
  __shared__ unsigned short smem[2*BM*BK];
  unsigned short* As = smem;
  unsigned short* Bs = smem + BM*BK;
  int w = xcd_chunk(blockIdx.x, NMB*NBN2);
  int bm = w / NBN2, bn = w % NBN2;
  int tid = threadIdx.x, wid = tid >> 6, lane = tid & 63;
  int s0 = bm * BM;
  int e = 0;
  #pragma unroll
  for (int i = 1; i < NEXP; ++i) if (s0 >= offs[i]) e = i;
  int kcs = ((lane & 7) ^ (lane >> 3)) * 8;
  int ldst = (lane & 7) * 8;
  const unsigned short* w2te = w2t + ((size_t)e*DIM + (size_t)bn*BN) * HID;

  f32x4 acc[4][4];
  #pragma unroll
  for (int m=0;m<4;m++)
    #pragma unroll
    for (int n=0;n<4;n++) acc[m][n] = (f32x4){0.f,0.f,0.f,0.f};

  int wr = wid >> 1, wc = wid & 1;
  int xr = (lane & 7) * 8;

  for (int kt = 0; kt < HID/BK; ++kt) {
    int k0 = kt * BK;
    #pragma unroll
    for (int i = 0; i < 4; ++i) {
      int r = (i*4 + wid)*8 + (lane >> 3);
      gload_lds16(h + (size_t)(s0 + r)*HID + k0 + kcs, &As[r*BK + ldst]);
      gload_lds16(w2te + (size_t)r*HID + k0 + kcs, &Bs[r*BK + ldst]);
    }
    __syncthreads();
    #pragma unroll
    for (int ks = 0; ks < 2; ++ks) {
      int kk = (ks*32 + (lane >> 4)*8) ^ xr;
      bf16x8 a[4], b[4];
      #pragma unroll
      for (int m=0;m<4;m++) a[m] = *(const bf16x8*)&As[(wr*64 + m*16 + (lane&15))*BK + kk];
      #pragma unroll
      for (int n=0;n<4;n++) b[n] = *(const bf16x8*)&Bs[(wc*64 + n*16 + (lane&15))*BK + kk];
      #pragma unroll
      for (int m=0;m<4;m++)
        #pragma unroll
        for (int n=0;n<4;n++)
          acc[m][n] = __builtin_amdgcn_mfma_f32_16x16x32_bf16(a[m], b[n], acc[m][n], 0,0,0);
    }
    __syncthreads();
  }

  unsigned short* ct = smem;
  #pragma unroll
  for (int m=0;m<4;m++){
    int row0 = wr*64 + m*16 + (lane>>4)*4;
    #pragma unroll
    for (int n=0;n<4;n++){
      int lcol = wc*64 + n*16 + (lane&15);
      float bias = b2[e*DIM + bn*BN + lcol];
      #pragma unroll
      for (int r=0;r<4;r++){
        int row = row0 + r;
        int pc = (lcol >> 3) ^ (row & 7);
        ct[row*BN + (pc<<3) + (lcol&7)] = f2bf(acc[m][n][r] + bias);
      }
    }
  }
  __syncthreads();
  int cchunk = tid & 15, rbase = tid >> 4;
  unsigned short* yb = ybuf + (size_t)s0*DIM + bn*BN;
  #pragma unroll
  for (int j=0;j<8;j++){
    int row = rbase + j*16;
    int pc = cchunk ^ (row & 7);
    bf16x8 v = *(const bf16x8*)&ct[row*BN + (pc<<3)];
    *(bf16x8*)&yb[(size_t)row*DIM + cchunk*8] = v;
  }
}

// ---------------- combine: out[t] = g0*y[s0] + g1*y[s1] ---- (R11-verified)
__global__ __launch_bounds__(256) void k_combine(
    const unsigned short* __restrict__ ybuf, const int* __restrict__ tok_slot,
    const float* __restrict__ top_gate, float* __restrict__ out) {
  int gid = blockIdx.x * 256 + threadIdx.x;
  int t = gid >> 6, j = (gid & 63) * 8;
  int s0 = tok_slot[t*2], s1 = tok_slot[t*2+1];
  float g0 = top_gate[t*2], g1 = top_gate[t*2+1];
  union { bf16x8 v; unsigned short us[8]; } y0, y1;
  y0.v = *(const bf16x8*)&ybuf[(size_t)s0*DIM + j];
  y1.v = *(const bf16x8*)&ybuf[(size_t)s1*DIM + j];
  float4 o0, o1;
  float* op0 = &o0.x;
  float* op1 = &o1.x;
  #pragma unroll
  for (int i = 0; i < 4; ++i) op0[i] = g0*bf2f(y0.us[i])   + g1*bf2f(y1.us[i]);
  #pragma unroll
  for (int i = 0; i < 4; ++i) op1[i] = g0*bf2f(y0.us[4+i]) + g1*bf2f(y1.us[4+i]);
  float4* dst = (float4*)&out[(size_t)t*DIM + j];
  dst[0] = o0; dst[1] = o1;
}

extern "C" void kernel_launch(void* const* d_in, const int* in_sizes, int n_in,
                              void* d_out, int out_size, void* d_ws, size_t ws_size,
                              hipStream_t stream) {
  const float* x   = (const float*)d_in[0];
  const float* noi = (const float*)d_in[1];
  const float* Wr  = (const float*)d_in[2];
  const float* br  = (const float*)d_in[3];
  const float* Wn  = (const float*)d_in[4];
  const float* bnb = (const float*)d_in[5];
  const float* W1  = (const float*)d_in[6];
  const float* b1  = (const float*)d_in[7];
  const float* W2  = (const float*)d_in[8];
  const float* b2  = (const float*)d_in[9];
  float* out = (float*)d_out;
  (void)in_sizes; (void)n_in; (void)ws_size; (void)out_size;

  char* ws = (char*)d_ws;
  size_t off = 0;
  auto alloc = [&](size_t bytes) -> void* {
    void* p = ws + off; off += (bytes + 255) & ~(size_t)255; return p;
  };
  // ORDER MATTERS: w1t then xb (both dead after gemm1) form a contiguous
  // 37,748,736 B region that ybuf (34,865,152 B) aliases. w2t comes AFTER.
  unsigned short* w1t  = (unsigned short*)alloc((size_t)NEXP*HID*DIM*2);  // 21.0 MB @0
  unsigned short* xb   = (unsigned short*)alloc((size_t)N_TOK*DIM*2);     // 16.8 MB
  unsigned short* w2t  = (unsigned short*)alloc((size_t)NEXP*DIM*HID*2);  // 21.0 MB (live in gemm2)
  unsigned short* hbuf = (unsigned short*)alloc((size_t)MAXSLOT*HID*2);   // 139.5 MB
  float* wrt = (float*)alloc(NEXP*DIM*4);
  float* wnt = (float*)alloc(NEXP*DIM*4);
  int*   top_idx  = (int*)alloc(N_TOK*2*4);
  float* top_gate = (float*)alloc(N_TOK*2*4);
  int*   slot_token = (int*)alloc((size_t)MAXSLOT*4);
  int*   tok_slot   = (int*)alloc((size_t)N_TOK*2*4);
  int*   ctrl = (int*)alloc(64*4);
  int* counts  = ctrl;        // [10]
  int* cursors = ctrl + 10;   // [10]
  int* offs    = ctrl + 20;   // [11]
  unsigned short* ybuf = w1t;   // alias checked numerically (R8 lesson)

  hipMemsetAsync(ctrl, 0, 64*4, stream);
  hipMemsetAsync(slot_token, 0xFF, (size_t)MAXSLOT*4, stream);  // -1 fill

  k_prep<<<NT_W1 + NT_W2 + 1, 256, 0, stream>>>(W1, w1t, W2, w2t, Wr, Wn, wrt, wnt);
  k_router2x<<<N_TOK/RT_TOK, 256, 0, stream>>>(x, noi, wrt, wnt, br, bnb,
                                               top_idx, top_gate, counts, xb);
  k_scatter2<<<N_TOK/256, 256, 0, stream>>>(top_idx, counts, cursors, offs,
                                            slot_token, tok_slot);
  k_gemm1<<<NMB*NBN1, 256, 0, stream>>>(xb, w1t, b1, slot_token, offs, hbuf);
  k_gemm2<<<NMB*NBN2, 256, 0, stream>>>(hbuf, w2t, b2, offs, ybuf);
  k_combine<<<(N_TOK*64)/256, 256, 0, stream>>>(ybuf, tok_slot, top_gate, out);
}